// Round 3
// 539.771 us; speedup vs baseline: 1.6056x; 1.6056x over previous
//
#include <hip/hip_runtime.h>

#define BATCH 2048

typedef unsigned short u16;
typedef __attribute__((ext_vector_type(8))) short bf16x8;  // 8 bf16 = 4 VGPR
typedef __attribute__((ext_vector_type(4))) float f32x4;   // MFMA 16x16 acc

static __device__ __forceinline__ float b2f(u16 h) {
  union { unsigned u; float f; } x; x.u = ((unsigned)h) << 16; return x.f;
}
static __device__ __forceinline__ u16 f2b(float f) {  // RNE fp32->bf16
  union { float f; unsigned u; } x; x.f = f;
  return (u16)((x.u + 0x7fffu + ((x.u >> 16) & 1u)) >> 16);
}
static __device__ __forceinline__ void split2(float v, u16& h, u16& l) {
  h = f2b(v); l = f2b(v - b2f(h));
}
// 8 bf16 from LDS at 8B alignment (2x ds_read_b64)
static __device__ __forceinline__ bf16x8 ld8u(const u16* p, int idx) {
  union { bf16x8 v; ushort4 u[2]; } x;
  x.u[0] = *(const ushort4*)(p + idx);
  x.u[1] = *(const ushort4*)(p + idx + 4);
  return x.v;
}

// ---------------------------------------------------------------------------
// Pre-split conv weights into direct-conv position-major layouts (hi plane
// then lo plane):
//   W1d [8 ky][32 oc][32 k]  k = kx*3+c for k<24, zeros k>=24  (8192 + 8192)
//   W2d [16 pos][64 oc][32 cc]                                (32768 + 32768)
//   W3d [9 pos][2 kc][64 oc][32 j]  cc = kc*32+j              (36864 + 36864)
// 77824 threads = grid 304 x 256.
// ---------------------------------------------------------------------------
__global__ void wsplit_kernel(const float* __restrict__ k1,
                              const float* __restrict__ k2,
                              const float* __restrict__ k3,
                              u16* __restrict__ W1d, u16* __restrict__ W2d,
                              u16* __restrict__ W3d)
{
  int id = blockIdx.x * 256 + threadIdx.x;   // 0..77823
  float v; u16 *dh, *dl;
  if (id < 8192) {
    int ky = id >> 10, oc = (id >> 5) & 31, kk = id & 31;
    if (kk < 24) {
      int kx = kk / 3, c = kk - kx * 3;
      v = k1[oc * 192 + c * 64 + ky * 8 + kx];
    } else v = 0.f;
    dh = W1d + id; dl = W1d + 8192 + id;
  } else if (id < 40960) {
    int i = id - 8192;
    int pos = i >> 11, oc = (i >> 5) & 63, cc = i & 31;
    int ky = pos >> 2, kx = pos & 3;
    v = k2[oc * 512 + cc * 16 + ky * 4 + kx];
    dh = W2d + i; dl = W2d + 32768 + i;
  } else {
    int i = id - 40960;                      // ((pos*2+kc)*64+oc)*32 + j
    int j = i & 31, oc = (i >> 5) & 63, kc = (i >> 11) & 1, pos = i >> 12;
    int ky = pos / 3, kx = pos - ky * 3;
    v = k3[oc * 576 + (kc * 32 + j) * 9 + ky * 3 + kx];
    dh = W3d + i; dl = W3d + 36864 + i;
  }
  u16 h, l; split2(v, h, l); *dh = h; *dl = l;
}

// ---------------------------------------------------------------------------
// Fused conv1+conv2+conv3, one block per image, 256 thr = 4 waves.
// All intermediates in LDS:
//   a1 [400 px][36] hi/lo u16 (stride 36: 2-way banks on stride-2 row reads)
//   SH region: conv1 il band [20 rows][252] NHWC hi/lo, then a2 [81][72] hi/lo
// Direct conv: loop kernel positions; A-frag = shifted LDS row read, B-frag =
// global 16B load from L2-hot W*d. No barriers inside position loops.
// ---------------------------------------------------------------------------
__global__ __launch_bounds__(256) void conv_fused_kernel(
    const float* __restrict__ state, const u16* __restrict__ W1d,
    const u16* __restrict__ W2d, const u16* __restrict__ W3d,
    const float* __restrict__ c1, const float* __restrict__ c2,
    const float* __restrict__ c3, float* __restrict__ a3)
{
  __shared__ __align__(16) u16 A1h[14400], A1l[14400];  // [400][36]
  __shared__ __align__(16) u16 SHa[5832], SHb[5832];    // il [20][252] / a2 [81][72]

  const int b = blockIdx.x, t = threadIdx.x;
  const int lane = t & 63, w = t >> 6, q = lane >> 4, n = lane & 15;

  // Zero the il tail: conv1's zero-weight pad lanes (kk>=24, row 19, pxx=19)
  // read SHa/SHb[5040..5047], which the il loader never writes. Stale LDS can
  // hold Inf/NaN bf16 patterns -> 0*Inf = NaN -> relu flushes pixel to 0.
  // The tail is never overwritten during conv1, so one zeroing covers 5 bands.
  for (int i = t; i < 792; i += 256) { SHa[5040 + i] = 0; SHb[5040 + i] = 0; }

  // ================= conv1: 84x84x3 -> 20x20x32, 8x8 s4, 5 bands =========
  // tiles: w0: pt{0,1} x ot{0,1}; w1: pt{2,3} x ot{0,1}; w2: pt4 ot0; w3: pt4 ot1
  const bool two = (w < 2);
  const int nPT = two ? 2 : 1, nOT = two ? 2 : 1;
  int ptv[2], otv[2];
  ptv[0] = two ? 2 * w     : 4;
  ptv[1] = two ? 2 * w + 1 : 4;
  otv[0] = two ? 0 : (w - 2);
  otv[1] = 1;

  int aoff1[2];
  #pragma unroll
  for (int i = 0; i < 2; ++i) {
    int px = ptv[i] * 16 + n; if (px > 79) px = 79;
    int py = (px * 205) >> 12, pxx = px - py * 20;
    aoff1[i] = (py * 4) * 252 + pxx * 12 + q * 8;
  }
  float c1v[2];
  #pragma unroll
  for (int j = 0; j < 2; ++j) c1v[j] = c1[otv[j] * 16 + n];

  for (int by = 0; by < 5; ++by) {
    __syncthreads();
    const float4* sp = (const float4*)(state + (size_t)b * 21168 + by * 4032);
    #pragma unroll
    for (int pass = 0; pass < 5; ++pass) {
      int i = t + pass * 256;
      if (i < 1260) {
        float4 v = sp[i];
        u16 h0, l0, h1, l1, h2, l2, h3, l3;
        split2(v.x, h0, l0); split2(v.y, h1, l1);
        split2(v.z, h2, l2); split2(v.w, h3, l3);
        ushort4 hh; hh.x = h0; hh.y = h1; hh.z = h2; hh.w = h3;
        ushort4 ll; ll.x = l0; ll.y = l1; ll.z = l2; ll.w = l3;
        *(ushort4*)&SHa[i * 4] = hh;
        *(ushort4*)&SHb[i * 4] = ll;
      }
    }
    __syncthreads();

    f32x4 acc[2][2] = {};
    for (int ky = 0; ky < 8; ++ky) {
      bf16x8 bh[2], bo[2];
      #pragma unroll
      for (int j = 0; j < 2; ++j) if (j < nOT) {
        int ob = (ky * 32 + otv[j] * 16 + n) * 32 + q * 8;
        bh[j] = *(const bf16x8*)(W1d + ob);
        bo[j] = *(const bf16x8*)(W1d + 8192 + ob);
      }
      #pragma unroll
      for (int i = 0; i < 2; ++i) if (i < nPT) {
        bf16x8 ah = ld8u(SHa, aoff1[i] + ky * 252);
        bf16x8 al = ld8u(SHb, aoff1[i] + ky * 252);
        #pragma unroll
        for (int j = 0; j < 2; ++j) if (j < nOT) {
          acc[i][j] = __builtin_amdgcn_mfma_f32_16x16x32_bf16(ah, bh[j], acc[i][j], 0, 0, 0);
          acc[i][j] = __builtin_amdgcn_mfma_f32_16x16x32_bf16(ah, bo[j], acc[i][j], 0, 0, 0);
          acc[i][j] = __builtin_amdgcn_mfma_f32_16x16x32_bf16(al, bh[j], acc[i][j], 0, 0, 0);
        }
      }
    }
    // epilogue: bias+relu, split, store a1 [px][36]
    #pragma unroll
    for (int i = 0; i < 2; ++i) if (i < nPT)
      #pragma unroll
      for (int j = 0; j < 2; ++j) if (j < nOT) {
        int oc = otv[j] * 16 + n;
        #pragma unroll
        for (int r = 0; r < 4; ++r) {
          int px = by * 80 + ptv[i] * 16 + q * 4 + r;
          float v = fmaxf(acc[i][j][r] + c1v[j], 0.f);
          u16 h, l; split2(v, h, l);
          A1h[px * 36 + oc] = h; A1l[px * 36 + oc] = l;
        }
      }
  }
  __syncthreads();

  // ================= conv2: 20x20x32 -> 9x9x64, 4x4 s2 ===================
  // tiles: wave = pt{0,1,2}/{3,4,5} (w>>1) x ot{0,1}/{2,3} (w&1)
  {
    const int p20 = (w >> 1) * 3, o20 = (w & 1) * 2;
    int aoff2[3];
    #pragma unroll
    for (int i = 0; i < 3; ++i) {
      int px = (p20 + i) * 16 + n; if (px > 80) px = 80;
      int py = (px * 7282) >> 16, pxx = px - py * 9;
      aoff2[i] = 2 * (py * 20 + pxx) * 36 + q * 8;
    }
    float c2v[2];
    #pragma unroll
    for (int j = 0; j < 2; ++j) c2v[j] = c2[(o20 + j) * 16 + n];

    f32x4 acc2[3][2] = {};
    for (int pos = 0; pos < 16; ++pos) {
      const int o = ((pos >> 2) * 20 + (pos & 3)) * 36;
      bf16x8 bh[2], bo[2];
      #pragma unroll
      for (int j = 0; j < 2; ++j) {
        int ob = pos * 2048 + ((o20 + j) * 16 + n) * 32 + q * 8;
        bh[j] = *(const bf16x8*)(W2d + ob);
        bo[j] = *(const bf16x8*)(W2d + 32768 + ob);
      }
      #pragma unroll
      for (int i = 0; i < 3; ++i) {
        bf16x8 ah = ld8u(A1h, aoff2[i] + o);
        bf16x8 al = ld8u(A1l, aoff2[i] + o);
        #pragma unroll
        for (int j = 0; j < 2; ++j) {
          acc2[i][j] = __builtin_amdgcn_mfma_f32_16x16x32_bf16(ah, bh[j], acc2[i][j], 0, 0, 0);
          acc2[i][j] = __builtin_amdgcn_mfma_f32_16x16x32_bf16(ah, bo[j], acc2[i][j], 0, 0, 0);
          acc2[i][j] = __builtin_amdgcn_mfma_f32_16x16x32_bf16(al, bh[j], acc2[i][j], 0, 0, 0);
        }
      }
    }
    // epilogue: a2 [81][72] into SH region (il is dead)
    #pragma unroll
    for (int i = 0; i < 3; ++i)
      #pragma unroll
      for (int j = 0; j < 2; ++j) {
        int oc = (o20 + j) * 16 + n;
        #pragma unroll
        for (int r = 0; r < 4; ++r) {
          int px = (p20 + i) * 16 + q * 4 + r;
          if (px < 81) {
            float v = fmaxf(acc2[i][j][r] + c2v[j], 0.f);
            u16 h, l; split2(v, h, l);
            SHa[px * 72 + oc] = h; SHb[px * 72 + oc] = l;
          }
        }
      }
  }
  __syncthreads();

  // ================= conv3: 9x9x64 -> 7x7x64, 3x3 s1 =====================
  // tiles: wave = pt{0,1}/{2,3} (w>>1) x ot{0,1}/{2,3} (w&1)
  {
    const int p30 = (w >> 1) * 2, o30 = (w & 1) * 2;
    int aoff3[2];
    #pragma unroll
    for (int i = 0; i < 2; ++i) {
      int px = (p30 + i) * 16 + n; if (px > 48) px = 48;
      int py = (px * 74) >> 9, pxx = px - py * 7;
      aoff3[i] = (py * 9 + pxx) * 72 + q * 8;
    }
    float c3v[2];
    #pragma unroll
    for (int j = 0; j < 2; ++j) c3v[j] = c3[(o30 + j) * 16 + n];

    f32x4 acc3[2][2] = {};
    for (int pos = 0; pos < 9; ++pos) {
      int ky = pos / 3, kx = pos - ky * 3;
      const int o = (ky * 9 + kx) * 72;
      #pragma unroll
      for (int kc = 0; kc < 2; ++kc) {
        bf16x8 bh[2], bo[2];
        #pragma unroll
        for (int j = 0; j < 2; ++j) {
          int ob = (pos * 2 + kc) * 2048 + ((o30 + j) * 16 + n) * 32 + q * 8;
          bh[j] = *(const bf16x8*)(W3d + ob);
          bo[j] = *(const bf16x8*)(W3d + 36864 + ob);
        }
        #pragma unroll
        for (int i = 0; i < 2; ++i) {
          bf16x8 ah = *(const bf16x8*)&SHa[aoff3[i] + o + kc * 32];  // 16B aligned
          bf16x8 al = *(const bf16x8*)&SHb[aoff3[i] + o + kc * 32];
          #pragma unroll
          for (int j = 0; j < 2; ++j) {
            acc3[i][j] = __builtin_amdgcn_mfma_f32_16x16x32_bf16(ah, bh[j], acc3[i][j], 0, 0, 0);
            acc3[i][j] = __builtin_amdgcn_mfma_f32_16x16x32_bf16(ah, bo[j], acc3[i][j], 0, 0, 0);
            acc3[i][j] = __builtin_amdgcn_mfma_f32_16x16x32_bf16(al, bh[j], acc3[i][j], 0, 0, 0);
          }
        }
      }
    }
    float* op = a3 + (size_t)b * 3136;
    #pragma unroll
    for (int i = 0; i < 2; ++i)
      #pragma unroll
      for (int j = 0; j < 2; ++j) {
        int oc = (o30 + j) * 16 + n;
        #pragma unroll
        for (int r = 0; r < 4; ++r) {
          int px = (p30 + i) * 16 + q * 4 + r;
          if (px < 49) op[oc * 49 + px] = fmaxf(acc3[i][j][r] + c3v[j], 0.f);
        }
      }
  }
}

// ---------------------------------------------------------------------------
// Group samples by expert (single block, 1024 thr). Auto-detect i32/i64 rm.
// ---------------------------------------------------------------------------
__global__ void group_kernel(const void* __restrict__ rmv,
                             int* __restrict__ counts, int* __restrict__ idxb)
{
  __shared__ int isI32;
  const int t = threadIdx.x;
  if (t == 0) isI32 = 0;
  if (t < 8) counts[t] = 0;
  __syncthreads();
  unsigned long long v = ((const unsigned long long*)rmv)[t];
  if (v >= 8ull) isI32 = 1;
  __syncthreads();
  const int i32 = isI32;
  for (int b = t; b < BATCH; b += 1024) {
    int e = i32 ? ((const int*)rmv)[b] : (int)((const long long*)rmv)[b];
    int pos = atomicAdd(&counts[e], 1);
    idxb[e * BATCH + pos] = b;
  }
}

// ---------------------------------------------------------------------------
// GEMM1 (grouped, fp32): H1[s][64] += a3[s][k]*W1[e][k][64], K-split 7x448.
// ---------------------------------------------------------------------------
__global__ __launch_bounds__(256) void gemm1_grp_kernel(
    const float* __restrict__ a3, const int* __restrict__ counts,
    const int* __restrict__ idxb, const float* __restrict__ W1,
    float* __restrict__ H1)
{
  __shared__ __align__(16) float At[32 * 68];
  __shared__ __align__(16) float Bw[32 * 64];
  __shared__ int s_id[64];
  const int e  = blockIdx.x >> 5;
  const int tl = blockIdx.x & 31;
  const int ks = blockIdx.y;
  const int cnt = counts[e];
  const int n0 = tl * 64;
  if (n0 >= cnt) return;
  const int m = min(64, cnt - n0);
  const int t = threadIdx.x;
  if (t < 64) s_id[t] = idxb[e * BATCH + n0 + min(t, m - 1)];
  __syncthreads();

  const int tx = t & 15, ty = t >> 4;
  const int c0 = tx * 4, r0 = ty * 4;
  const float* W1e = W1 + (size_t)e * 3136 * 64;
  float acc[4][4] = {};
  const int kbase = ks * 448;

  for (int k0 = kbase; k0 < kbase + 448; k0 += 32) {
    __syncthreads();
    {
      int i = t;
      #pragma unroll
      for (int pass = 0; pass < 2; ++pass, i += 256) {
        int r = i >> 3, k4 = (i & 7) * 4;
        float4 v = *(const float4*)(a3 + (size_t)s_id[r] * 3136 + k0 + k4);
        At[(k4 + 0) * 68 + r] = v.x; At[(k4 + 1) * 68 + r] = v.y;
        At[(k4 + 2) * 68 + r] = v.z; At[(k4 + 3) * 68 + r] = v.w;
      }
      int i2 = t;
      #pragma unroll
      for (int pass = 0; pass < 2; ++pass, i2 += 256) {
        int kk = i2 >> 4, h4 = (i2 & 15) * 4;
        *(float4*)&Bw[kk * 64 + h4] = *(const float4*)&W1e[(size_t)(k0 + kk) * 64 + h4];
      }
    }
    __syncthreads();
    #pragma unroll
    for (int kk = 0; kk < 32; ++kk) {
      float4 a = *(const float4*)&At[kk * 68 + r0];
      float4 bb = *(const float4*)&Bw[kk * 64 + c0];
      float av[4] = {a.x, a.y, a.z, a.w}, bv[4] = {bb.x, bb.y, bb.z, bb.w};
      #pragma unroll
      for (int ii = 0; ii < 4; ++ii)
        #pragma unroll
        for (int j = 0; j < 4; ++j)
          acc[ii][j] += av[ii] * bv[j];
    }
  }

  #pragma unroll
  for (int ii = 0; ii < 4; ++ii) {
    if (r0 + ii < m) {
      int s = s_id[r0 + ii];
      #pragma unroll
      for (int j = 0; j < 4; ++j)
        atomicAdd(&H1[(size_t)s * 64 + c0 + j], acc[ii][j]);
    }
  }
}

// ---------------------------------------------------------------------------
// MLP tail (grouped): bias+relu H1, layers 2..5, layer 6, scatter to out.
// ---------------------------------------------------------------------------
__global__ __launch_bounds__(256) void tail_grp_kernel(
    const float* __restrict__ H1, const int* __restrict__ counts,
    const int* __restrict__ idxb, const float* __restrict__ B1,
    const float* __restrict__ W2, const float* __restrict__ B2,
    const float* __restrict__ W3, const float* __restrict__ B3,
    const float* __restrict__ W4, const float* __restrict__ B4,
    const float* __restrict__ W5, const float* __restrict__ B5,
    const float* __restrict__ W6, const float* __restrict__ B6,
    float* __restrict__ out)
{
  __shared__ __align__(16) float Wl[4096];
  __shared__ float bl[64];
  __shared__ float W6l[384];
  __shared__ float B6l[8];
  __shared__ __align__(16) float Ht0[64 * 68];
  __shared__ __align__(16) float Ht1[64 * 68];
  __shared__ int s_id[64];

  const int e  = blockIdx.x >> 5;
  const int tl = blockIdx.x & 31;
  const int cnt = counts[e];
  const int n0 = tl * 64;
  if (n0 >= cnt) return;
  const int m = min(64, cnt - n0);
  const int t = threadIdx.x;
  if (t < 64) s_id[t] = idxb[e * BATCH + n0 + min(t, m - 1)];
  for (int i = t; i < 384; i += 256) W6l[i] = W6[e * 384 + i];
  if (t < 6)   B6l[t] = B6[e * 6 + t];
  __syncthreads();

  #pragma unroll
  for (int p = 0; p < 16; ++p) {
    int i = t + p * 256;
    int c = i & 63, r = i >> 6;
    Ht0[c * 68 + r] = fmaxf(H1[(size_t)s_id[r] * 64 + c] + B1[e * 64 + c], 0.f);
  }

  const int tx = t & 15, ty = t >> 4;
  const int c0 = tx * 4, r0 = ty * 4;
  const float* Ws[4] = {W2, W3, W4, W5};
  const float* Bs[4] = {B2, B3, B4, B5};
  float* Hc = Ht0; float* Hn = Ht1;

  for (int L = 0; L < 4; ++L) {
    __syncthreads();
    const float* We = Ws[L] + (size_t)e * 4096;
    for (int i = t; i < 1024; i += 256)
      *(float4*)&Wl[i * 4] = *(const float4*)&We[i * 4];
    if (t < 64) bl[t] = Bs[L][e * 64 + t];
    __syncthreads();

    float acc[4][4] = {};
    #pragma unroll 4
    for (int kk = 0; kk < 64; ++kk) {
      float4 a = *(const float4*)&Hc[kk * 68 + r0];
      float4 bb = *(const float4*)&Wl[kk * 64 + c0];
      float av[4] = {a.x, a.y, a.z, a.w}, bv[4] = {bb.x, bb.y, bb.z, bb.w};
      #pragma unroll
      for (int ii = 0; ii < 4; ++ii)
        #pragma unroll
        for (int j = 0; j < 4; ++j)
          acc[ii][j] += av[ii] * bv[j];
    }
    __syncthreads();
    #pragma unroll
    for (int j = 0; j < 4; ++j) {
      float bias = bl[c0 + j];
      #pragma unroll
      for (int ii = 0; ii < 4; ++ii)
        Hn[(c0 + j) * 68 + r0 + ii] = fmaxf(acc[ii][j] + bias, 0.f);
    }
    float* tmp = Hc; Hc = Hn; Hn = tmp;
  }
  __syncthreads();

  const int r = t & 63, aa = t >> 6;
  float s0v = 0.f, s1v = 0.f;
  for (int k = 0; k < 64; ++k) {
    float h = Hc[k * 68 + r];
    s0v += h * W6l[k * 6 + aa];
    s1v += h * W6l[k * 6 + ((aa < 2) ? aa + 4 : aa)];
  }
  if (r < m) {
    int s = s_id[r];
    out[s * 6 + aa] = s0v + B6l[aa];
    if (aa < 2) out[s * 6 + aa + 4] = s1v + B6l[aa + 4];
  }
}

// ---------------------------------------------------------------------------
extern "C" void kernel_launch(void* const* d_in, const int* in_sizes, int n_in,
                              void* d_out, int out_size, void* d_ws, size_t ws_size,
                              hipStream_t stream) {
  const float* state = (const float*)d_in[0];
  const void*  rm    = d_in[1];
  const float* k1 = (const float*)d_in[2];
  const float* c1 = (const float*)d_in[3];
  const float* k2 = (const float*)d_in[4];
  const float* c2 = (const float*)d_in[5];
  const float* k3 = (const float*)d_in[6];
  const float* c3 = (const float*)d_in[7];
  const float* W1 = (const float*)d_in[8];
  const float* B1 = (const float*)d_in[9];
  const float* W2 = (const float*)d_in[10];
  const float* B2 = (const float*)d_in[11];
  const float* W3 = (const float*)d_in[12];
  const float* B3 = (const float*)d_in[13];
  const float* W4 = (const float*)d_in[14];
  const float* B4 = (const float*)d_in[15];
  const float* W5 = (const float*)d_in[16];
  const float* B5 = (const float*)d_in[17];
  const float* W6 = (const float*)d_in[18];
  const float* B6 = (const float*)d_in[19];

  // workspace layout (~26.6 MB)
  char* ws = (char*)d_ws;
  float* a3   = (float*)(ws);                  // 25,690,112
  float* H1   = (float*)(ws + 25690112);       //    524,288
  int* counts = (int*)  (ws + 26214400);       //         32
  int* idxb   = (int*)  (ws + 26214432);       //     65,536 (+pad)
  u16* W1d    = (u16*)  (ws + 26280064);       //     32,768
  u16* W2d    = (u16*)  (ws + 26312832);       //    131,072
  u16* W3d    = (u16*)  (ws + 26443904);       //    147,456 -> end 26,591,360

  wsplit_kernel<<<304, 256, 0, stream>>>(k1, k2, k3, W1d, W2d, W3d);
  hipMemsetAsync(H1, 0, BATCH * 64 * sizeof(float), stream);
  group_kernel<<<1, 1024, 0, stream>>>(rm, counts, idxb);

  conv_fused_kernel<<<2048, 256, 0, stream>>>(state, W1d, W2d, W3d,
                                              c1, c2, c3, a3);

  gemm1_grp_kernel<<<dim3(256, 7), 256, 0, stream>>>(a3, counts, idxb, W1, H1);
  tail_grp_kernel<<<256, 256, 0, stream>>>(H1, counts, idxb, B1,
                                           W2, B2, W3, B3, W4, B4, W5, B5,
                                           W6, B6, (float*)d_out);
}

// Round 5
// 489.112 us; speedup vs baseline: 1.7719x; 1.1036x over previous
//
#include <hip/hip_runtime.h>

#define BATCH 2048

typedef unsigned short u16;
typedef __attribute__((ext_vector_type(8))) short bf16x8;  // 8 bf16 = 4 VGPR
typedef __attribute__((ext_vector_type(4))) float f32x4;   // MFMA 16x16 acc

static __device__ __forceinline__ float b2f(u16 h) {
  union { unsigned u; float f; } x; x.u = ((unsigned)h) << 16; return x.f;
}
static __device__ __forceinline__ u16 f2b(float f) {  // RNE fp32->bf16
  union { float f; unsigned u; } x; x.f = f;
  return (u16)((x.u + 0x7fffu + ((x.u >> 16) & 1u)) >> 16);
}
static __device__ __forceinline__ void split2(float v, u16& h, u16& l) {
  h = f2b(v); l = f2b(v - b2f(h));
}
// 8 bf16 from LDS at 8B alignment (2x ds_read_b64)
static __device__ __forceinline__ bf16x8 ld8u(const u16* p, int idx) {
  union { bf16x8 v; ushort4 u[2]; } x;
  x.u[0] = *(const ushort4*)(p + idx);
  x.u[1] = *(const ushort4*)(p + idx + 4);
  return x.v;
}

// ---------------------------------------------------------------------------
// Pre-split conv weights into direct-conv position-major layouts (hi plane
// then lo plane):
//   W1d [8 ky][32 oc][32 k]  k = kx*3+c for k<24, zeros k>=24  (8192 + 8192)
//   W2d [16 pos][64 oc][32 cc]                                (32768 + 32768)
//   W3d [9 pos][2 kc][64 oc][32 j]  cc = kc*32+j              (36864 + 36864)
// 77824 threads = grid 304 x 256.
// ---------------------------------------------------------------------------
__global__ void wsplit_kernel(const float* __restrict__ k1,
                              const float* __restrict__ k2,
                              const float* __restrict__ k3,
                              u16* __restrict__ W1d, u16* __restrict__ W2d,
                              u16* __restrict__ W3d)
{
  int id = blockIdx.x * 256 + threadIdx.x;   // 0..77823
  float v; u16 *dh, *dl;
  if (id < 8192) {
    int ky = id >> 10, oc = (id >> 5) & 31, kk = id & 31;
    if (kk < 24) {
      int kx = kk / 3, c = kk - kx * 3;
      v = k1[oc * 192 + c * 64 + ky * 8 + kx];
    } else v = 0.f;
    dh = W1d + id; dl = W1d + 8192 + id;
  } else if (id < 40960) {
    int i = id - 8192;
    int pos = i >> 11, oc = (i >> 5) & 63, cc = i & 31;
    int ky = pos >> 2, kx = pos & 3;
    v = k2[oc * 512 + cc * 16 + ky * 4 + kx];
    dh = W2d + i; dl = W2d + 32768 + i;
  } else {
    int i = id - 40960;                      // ((pos*2+kc)*64+oc)*32 + j
    int j = i & 31, oc = (i >> 5) & 63, kc = (i >> 11) & 1, pos = i >> 12;
    int ky = pos / 3, kx = pos - ky * 3;
    v = k3[oc * 576 + (kc * 32 + j) * 9 + ky * 3 + kx];
    dh = W3d + i; dl = W3d + 36864 + i;
  }
  u16 h, l; split2(v, h, l); *dh = h; *dl = l;
}

// ---------------------------------------------------------------------------
// Fused conv1+conv2+conv3, one block per image, 512 thr = 8 waves.
// LDS unchanged (81,408 B -> 2 blocks/CU) but 16 waves/CU = 4 waves/SIMD.
// Per-phase wave->tile maps are balanced across 8 waves; one oc-tile per
// wave in conv2/conv3 so each wave loads ONE B-frag pair per position,
// software-pipelined (cur/next rotation) to hide the ~200cy L2 latency.
// ---------------------------------------------------------------------------
__global__ __launch_bounds__(512, 4) void conv_fused_kernel(
    const float* __restrict__ state, const u16* __restrict__ W1d,
    const u16* __restrict__ W2d, const u16* __restrict__ W3d,
    const float* __restrict__ c1, const float* __restrict__ c2,
    const float* __restrict__ c3, float* __restrict__ a3)
{
  __shared__ __align__(16) u16 A1h[14400], A1l[14400];  // [400][36]
  __shared__ __align__(16) u16 SHa[5832], SHb[5832];    // il [20][252] / a2 [81][72]

  const int b = blockIdx.x, t = threadIdx.x;
  const int lane = t & 63, w = t >> 6, q = lane >> 4, n = lane & 15;

  // Zero the il tail: conv1's zero-weight pad lanes (kk>=24, row 19, pxx=19)
  // read SHa/SHb[5040..5047], which the il loader never writes. Stale LDS can
  // hold Inf/NaN bf16 patterns -> 0*Inf = NaN -> relu flushes pixel to 0.
  for (int i = t; i < 792; i += 512) { SHa[5040 + i] = 0; SHb[5040 + i] = 0; }

  // ================= conv1: 84x84x3 -> 20x20x32, 8x8 s4, 5 bands =========
  // 10 tiles (pt 0..4 x ot 0..1) over 8 waves: w0:(0,0)+(4,0) w1:(0,1)+(4,1)
  // w2..7: single tile (1+((w-2)>>1), (w-2)&1). 2-tile waves share ot ->
  // one B-frag pair per wave per ky.
  const int nT1 = (w < 2) ? 2 : 1;
  int pt1[2], ot1[2];
  if (w < 2) { pt1[0] = 0; ot1[0] = w; pt1[1] = 4; ot1[1] = w; }
  else       { pt1[0] = 1 + ((w - 2) >> 1); ot1[0] = (w - 2) & 1;
               pt1[1] = pt1[0]; ot1[1] = ot1[0]; }

  int aoff1[2];
  #pragma unroll
  for (int i = 0; i < 2; ++i) {
    int px = pt1[i] * 16 + n;                 // <= 79
    int py = (px * 205) >> 12, pxx = px - py * 20;
    aoff1[i] = (py * 4) * 252 + pxx * 12 + q * 8;
  }
  float c1v[2];
  #pragma unroll
  for (int j = 0; j < 2; ++j) c1v[j] = c1[ot1[j] * 16 + n];
  const int ob1 = (ot1[0] * 16 + n) * 32 + q * 8;   // + ky*1024

  for (int by = 0; by < 5; ++by) {
    __syncthreads();
    const float4* sp = (const float4*)(state + (size_t)b * 21168 + by * 4032);
    #pragma unroll
    for (int pass = 0; pass < 3; ++pass) {
      int i = t + pass * 512;
      if (i < 1260) {
        float4 v = sp[i];
        u16 h0, l0, h1, l1, h2, l2, h3, l3;
        split2(v.x, h0, l0); split2(v.y, h1, l1);
        split2(v.z, h2, l2); split2(v.w, h3, l3);
        ushort4 hh; hh.x = h0; hh.y = h1; hh.z = h2; hh.w = h3;
        ushort4 ll; ll.x = l0; ll.y = l1; ll.z = l2; ll.w = l3;
        *(ushort4*)&SHa[i * 4] = hh;
        *(ushort4*)&SHb[i * 4] = ll;
      }
    }
    __syncthreads();

    f32x4 acc1[2] = {};
    bf16x8 bhc = *(const bf16x8*)(W1d + ob1);
    bf16x8 boc = *(const bf16x8*)(W1d + 8192 + ob1);
    for (int ky = 0; ky < 8; ++ky) {
      const int kyn = (ky < 7) ? ky + 1 : 7;
      bf16x8 bhn = *(const bf16x8*)(W1d + kyn * 1024 + ob1);
      bf16x8 bon = *(const bf16x8*)(W1d + 8192 + kyn * 1024 + ob1);
      #pragma unroll
      for (int i = 0; i < 2; ++i) if (i < nT1) {
        bf16x8 ah = ld8u(SHa, aoff1[i] + ky * 252);
        bf16x8 al = ld8u(SHb, aoff1[i] + ky * 252);
        acc1[i] = __builtin_amdgcn_mfma_f32_16x16x32_bf16(ah, bhc, acc1[i], 0, 0, 0);
        acc1[i] = __builtin_amdgcn_mfma_f32_16x16x32_bf16(ah, boc, acc1[i], 0, 0, 0);
        acc1[i] = __builtin_amdgcn_mfma_f32_16x16x32_bf16(al, bhc, acc1[i], 0, 0, 0);
      }
      bhc = bhn; boc = bon;
    }
    // epilogue: bias+relu, split, store a1 [px][36]
    #pragma unroll
    for (int i = 0; i < 2; ++i) if (i < nT1) {
      int oc = ot1[i] * 16 + n;
      #pragma unroll
      for (int r = 0; r < 4; ++r) {
        int px = by * 80 + pt1[i] * 16 + q * 4 + r;
        float v = fmaxf(acc1[i][r] + c1v[i], 0.f);
        u16 h, l; split2(v, h, l);
        A1h[px * 36 + oc] = h; A1l[px * 36 + oc] = l;
      }
    }
  }
  __syncthreads();

  // ================= conv2: 20x20x32 -> 9x9x64, 4x4 s2 ===================
  // 24 tiles (pt 0..5 x ot 0..3) over 8 waves: wave = 3 pt x 1 ot.
  {
    const int ot2 = w & 3, pg2 = (w >> 2) * 3;
    int aoff2[3];
    #pragma unroll
    for (int i = 0; i < 3; ++i) {
      int px = (pg2 + i) * 16 + n; if (px > 80) px = 80;
      int py = (px * 7282) >> 16, pxx = px - py * 9;
      aoff2[i] = 2 * (py * 20 + pxx) * 36 + q * 8;
    }
    const float c2v = c2[ot2 * 16 + n];
    const int ob2 = (ot2 * 16 + n) * 32 + q * 8;

    f32x4 acc2[3] = {};
    bf16x8 bhc = *(const bf16x8*)(W2d + ob2);
    bf16x8 boc = *(const bf16x8*)(W2d + 32768 + ob2);
    for (int pos = 0; pos < 16; ++pos) {
      const int posn = (pos < 15) ? pos + 1 : 15;
      bf16x8 bhn = *(const bf16x8*)(W2d + posn * 2048 + ob2);
      bf16x8 bon = *(const bf16x8*)(W2d + 32768 + posn * 2048 + ob2);
      const int o = ((pos >> 2) * 20 + (pos & 3)) * 36;
      #pragma unroll
      for (int i = 0; i < 3; ++i) {
        bf16x8 ah = ld8u(A1h, aoff2[i] + o);
        bf16x8 al = ld8u(A1l, aoff2[i] + o);
        acc2[i] = __builtin_amdgcn_mfma_f32_16x16x32_bf16(ah, bhc, acc2[i], 0, 0, 0);
        acc2[i] = __builtin_amdgcn_mfma_f32_16x16x32_bf16(ah, boc, acc2[i], 0, 0, 0);
        acc2[i] = __builtin_amdgcn_mfma_f32_16x16x32_bf16(al, bhc, acc2[i], 0, 0, 0);
      }
      bhc = bhn; boc = bon;
    }
    // epilogue: a2 [81][72] into SH region (il is dead)
    #pragma unroll
    for (int i = 0; i < 3; ++i) {
      int oc = ot2 * 16 + n;
      #pragma unroll
      for (int r = 0; r < 4; ++r) {
        int px = (pg2 + i) * 16 + q * 4 + r;
        if (px < 81) {
          float v = fmaxf(acc2[i][r] + c2v, 0.f);
          u16 h, l; split2(v, h, l);
          SHa[px * 72 + oc] = h; SHb[px * 72 + oc] = l;
        }
      }
    }
  }
  __syncthreads();

  // ================= conv3: 9x9x64 -> 7x7x64, 3x3 s1 =====================
  // 16 tiles (pt 0..3 x ot 0..3) over 8 waves: wave = 2 pt x 1 ot.
  {
    const int ot3 = w & 3, pg3 = (w >> 2) * 2;
    int aoff3[2];
    #pragma unroll
    for (int i = 0; i < 2; ++i) {
      int px = (pg3 + i) * 16 + n; if (px > 48) px = 48;
      int py = (px * 74) >> 9, pxx = px - py * 7;
      aoff3[i] = (py * 9 + pxx) * 72 + q * 8;
    }
    const float c3v = c3[ot3 * 16 + n];
    const int ob3 = (ot3 * 16 + n) * 32 + q * 8;

    f32x4 acc3[2] = {};
    bf16x8 bhc = *(const bf16x8*)(W3d + ob3);
    bf16x8 boc = *(const bf16x8*)(W3d + 36864 + ob3);
    for (int pk = 0; pk < 18; ++pk) {           // pk = pos*2 + kc
      const int pkn = (pk < 17) ? pk + 1 : 17;
      bf16x8 bhn = *(const bf16x8*)(W3d + pkn * 2048 + ob3);
      bf16x8 bon = *(const bf16x8*)(W3d + 36864 + pkn * 2048 + ob3);
      const int pos = pk >> 1, kc = pk & 1;
      const int ky = pos / 3, kx = pos - ky * 3;
      const int o = (ky * 9 + kx) * 72 + kc * 32;
      #pragma unroll
      for (int i = 0; i < 2; ++i) {
        bf16x8 ah = *(const bf16x8*)&SHa[aoff3[i] + o];  // 16B aligned
        bf16x8 al = *(const bf16x8*)&SHb[aoff3[i] + o];
        acc3[i] = __builtin_amdgcn_mfma_f32_16x16x32_bf16(ah, bhc, acc3[i], 0, 0, 0);
        acc3[i] = __builtin_amdgcn_mfma_f32_16x16x32_bf16(ah, boc, acc3[i], 0, 0, 0);
        acc3[i] = __builtin_amdgcn_mfma_f32_16x16x32_bf16(al, bhc, acc3[i], 0, 0, 0);
      }
      bhc = bhn; boc = bon;
    }
    float* op = a3 + (size_t)b * 3136;
    #pragma unroll
    for (int i = 0; i < 2; ++i) {
      int oc = ot3 * 16 + n;
      #pragma unroll
      for (int r = 0; r < 4; ++r) {
        int px = (pg3 + i) * 16 + q * 4 + r;
        if (px < 49) op[oc * 49 + px] = fmaxf(acc3[i][r] + c3v, 0.f);
      }
    }
  }
}

// ---------------------------------------------------------------------------
// Group samples by expert (single block, 1024 thr). Auto-detect i32/i64 rm.
// ---------------------------------------------------------------------------
__global__ void group_kernel(const void* __restrict__ rmv,
                             int* __restrict__ counts, int* __restrict__ idxb)
{
  __shared__ int isI32;
  const int t = threadIdx.x;
  if (t == 0) isI32 = 0;
  if (t < 8) counts[t] = 0;
  __syncthreads();
  unsigned long long v = ((const unsigned long long*)rmv)[t];
  if (v >= 8ull) isI32 = 1;
  __syncthreads();
  const int i32 = isI32;
  for (int b = t; b < BATCH; b += 1024) {
    int e = i32 ? ((const int*)rmv)[b] : (int)((const long long*)rmv)[b];
    int pos = atomicAdd(&counts[e], 1);
    idxb[e * BATCH + pos] = b;
  }
}

// ---------------------------------------------------------------------------
// GEMM1 (grouped, fp32): H1[s][64] += a3[s][k]*W1[e][k][64], K-split 7x448.
// ---------------------------------------------------------------------------
__global__ __launch_bounds__(256) void gemm1_grp_kernel(
    const float* __restrict__ a3, const int* __restrict__ counts,
    const int* __restrict__ idxb, const float* __restrict__ W1,
    float* __restrict__ H1)
{
  __shared__ __align__(16) float At[32 * 68];
  __shared__ __align__(16) float Bw[32 * 64];
  __shared__ int s_id[64];
  const int e  = blockIdx.x >> 5;
  const int tl = blockIdx.x & 31;
  const int ks = blockIdx.y;
  const int cnt = counts[e];
  const int n0 = tl * 64;
  if (n0 >= cnt) return;
  const int m = min(64, cnt - n0);
  const int t = threadIdx.x;
  if (t < 64) s_id[t] = idxb[e * BATCH + n0 + min(t, m - 1)];
  __syncthreads();

  const int tx = t & 15, ty = t >> 4;
  const int c0 = tx * 4, r0 = ty * 4;
  const float* W1e = W1 + (size_t)e * 3136 * 64;
  float acc[4][4] = {};
  const int kbase = ks * 448;

  for (int k0 = kbase; k0 < kbase + 448; k0 += 32) {
    __syncthreads();
    {
      int i = t;
      #pragma unroll
      for (int pass = 0; pass < 2; ++pass, i += 256) {
        int r = i >> 3, k4 = (i & 7) * 4;
        float4 v = *(const float4*)(a3 + (size_t)s_id[r] * 3136 + k0 + k4);
        At[(k4 + 0) * 68 + r] = v.x; At[(k4 + 1) * 68 + r] = v.y;
        At[(k4 + 2) * 68 + r] = v.z; At[(k4 + 3) * 68 + r] = v.w;
      }
      int i2 = t;
      #pragma unroll
      for (int pass = 0; pass < 2; ++pass, i2 += 256) {
        int kk = i2 >> 4, h4 = (i2 & 15) * 4;
        *(float4*)&Bw[kk * 64 + h4] = *(const float4*)&W1e[(size_t)(k0 + kk) * 64 + h4];
      }
    }
    __syncthreads();
    #pragma unroll
    for (int kk = 0; kk < 32; ++kk) {
      float4 a = *(const float4*)&At[kk * 68 + r0];
      float4 bb = *(const float4*)&Bw[kk * 64 + c0];
      float av[4] = {a.x, a.y, a.z, a.w}, bv[4] = {bb.x, bb.y, bb.z, bb.w};
      #pragma unroll
      for (int ii = 0; ii < 4; ++ii)
        #pragma unroll
        for (int j = 0; j < 4; ++j)
          acc[ii][j] += av[ii] * bv[j];
    }
  }

  #pragma unroll
  for (int ii = 0; ii < 4; ++ii) {
    if (r0 + ii < m) {
      int s = s_id[r0 + ii];
      #pragma unroll
      for (int j = 0; j < 4; ++j)
        atomicAdd(&H1[(size_t)s * 64 + c0 + j], acc[ii][j]);
    }
  }
}

// ---------------------------------------------------------------------------
// MLP tail (grouped): bias+relu H1, layers 2..5, layer 6, scatter to out.
// ---------------------------------------------------------------------------
__global__ __launch_bounds__(256) void tail_grp_kernel(
    const float* __restrict__ H1, const int* __restrict__ counts,
    const int* __restrict__ idxb, const float* __restrict__ B1,
    const float* __restrict__ W2, const float* __restrict__ B2,
    const float* __restrict__ W3, const float* __restrict__ B3,
    const float* __restrict__ W4, const float* __restrict__ B4,
    const float* __restrict__ W5, const float* __restrict__ B5,
    const float* __restrict__ W6, const float* __restrict__ B6,
    float* __restrict__ out)
{
  __shared__ __align__(16) float Wl[4096];
  __shared__ float bl[64];
  __shared__ float W6l[384];
  __shared__ float B6l[8];
  __shared__ __align__(16) float Ht0[64 * 68];
  __shared__ __align__(16) float Ht1[64 * 68];
  __shared__ int s_id[64];

  const int e  = blockIdx.x >> 5;
  const int tl = blockIdx.x & 31;
  const int cnt = counts[e];
  const int n0 = tl * 64;
  if (n0 >= cnt) return;
  const int m = min(64, cnt - n0);
  const int t = threadIdx.x;
  if (t < 64) s_id[t] = idxb[e * BATCH + n0 + min(t, m - 1)];
  for (int i = t; i < 384; i += 256) W6l[i] = W6[e * 384 + i];
  if (t < 6)   B6l[t] = B6[e * 6 + t];
  __syncthreads();

  #pragma unroll
  for (int p = 0; p < 16; ++p) {
    int i = t + p * 256;
    int c = i & 63, r = i >> 6;
    Ht0[c * 68 + r] = fmaxf(H1[(size_t)s_id[r] * 64 + c] + B1[e * 64 + c], 0.f);
  }

  const int tx = t & 15, ty = t >> 4;
  const int c0 = tx * 4, r0 = ty * 4;
  const float* Ws[4] = {W2, W3, W4, W5};
  const float* Bs[4] = {B2, B3, B4, B5};
  float* Hc = Ht0; float* Hn = Ht1;

  for (int L = 0; L < 4; ++L) {
    __syncthreads();
    const float* We = Ws[L] + (size_t)e * 4096;
    for (int i = t; i < 1024; i += 256)
      *(float4*)&Wl[i * 4] = *(const float4*)&We[i * 4];
    if (t < 64) bl[t] = Bs[L][e * 64 + t];
    __syncthreads();

    float acc[4][4] = {};
    #pragma unroll 4
    for (int kk = 0; kk < 64; ++kk) {
      float4 a = *(const float4*)&Hc[kk * 68 + r0];
      float4 bb = *(const float4*)&Wl[kk * 64 + c0];
      float av[4] = {a.x, a.y, a.z, a.w}, bv[4] = {bb.x, bb.y, bb.z, bb.w};
      #pragma unroll
      for (int ii = 0; ii < 4; ++ii)
        #pragma unroll
        for (int j = 0; j < 4; ++j)
          acc[ii][j] += av[ii] * bv[j];
    }
    __syncthreads();
    #pragma unroll
    for (int j = 0; j < 4; ++j) {
      float bias = bl[c0 + j];
      #pragma unroll
      for (int ii = 0; ii < 4; ++ii)
        Hn[(c0 + j) * 68 + r0 + ii] = fmaxf(acc[ii][j] + bias, 0.f);
    }
    float* tmp = Hc; Hc = Hn; Hn = tmp;
  }
  __syncthreads();

  const int r = t & 63, aa = t >> 6;
  float s0v = 0.f, s1v = 0.f;
  for (int k = 0; k < 64; ++k) {
    float h = Hc[k * 68 + r];
    s0v += h * W6l[k * 6 + aa];
    s1v += h * W6l[k * 6 + ((aa < 2) ? aa + 4 : aa)];
  }
  if (r < m) {
    int s = s_id[r];
    out[s * 6 + aa] = s0v + B6l[aa];
    if (aa < 2) out[s * 6 + aa + 4] = s1v + B6l[aa + 4];
  }
}

// ---------------------------------------------------------------------------
extern "C" void kernel_launch(void* const* d_in, const int* in_sizes, int n_in,
                              void* d_out, int out_size, void* d_ws, size_t ws_size,
                              hipStream_t stream) {
  const float* state = (const float*)d_in[0];
  const void*  rm    = d_in[1];
  const float* k1 = (const float*)d_in[2];
  const float* c1 = (const float*)d_in[3];
  const float* k2 = (const float*)d_in[4];
  const float* c2 = (const float*)d_in[5];
  const float* k3 = (const float*)d_in[6];
  const float* c3 = (const float*)d_in[7];
  const float* W1 = (const float*)d_in[8];
  const float* B1 = (const float*)d_in[9];
  const float* W2 = (const float*)d_in[10];
  const float* B2 = (const float*)d_in[11];
  const float* W3 = (const float*)d_in[12];
  const float* B3 = (const float*)d_in[13];
  const float* W4 = (const float*)d_in[14];
  const float* B4 = (const float*)d_in[15];
  const float* W5 = (const float*)d_in[16];
  const float* B5 = (const float*)d_in[17];
  const float* W6 = (const float*)d_in[18];
  const float* B6 = (const float*)d_in[19];

  // workspace layout (~26.6 MB)
  char* ws = (char*)d_ws;
  float* a3   = (float*)(ws);                  // 25,690,112
  float* H1   = (float*)(ws + 25690112);       //    524,288
  int* counts = (int*)  (ws + 26214400);       //         32
  int* idxb   = (int*)  (ws + 26214432);       //     65,536 (+pad)
  u16* W1d    = (u16*)  (ws + 26280064);       //     32,768
  u16* W2d    = (u16*)  (ws + 26312832);       //    131,072
  u16* W3d    = (u16*)  (ws + 26443904);       //    147,456 -> end 26,591,360

  wsplit_kernel<<<304, 256, 0, stream>>>(k1, k2, k3, W1d, W2d, W3d);
  hipMemsetAsync(H1, 0, BATCH * 64 * sizeof(float), stream);
  group_kernel<<<1, 1024, 0, stream>>>(rm, counts, idxb);

  conv_fused_kernel<<<2048, 512, 0, stream>>>(state, W1d, W2d, W3d,
                                              c1, c2, c3, a3);

  gemm1_grp_kernel<<<dim3(256, 7), 256, 0, stream>>>(a3, counts, idxb, W1, H1);
  tail_grp_kernel<<<256, 256, 0, stream>>>(H1, counts, idxb, B1,
                                           W2, B2, W3, B3, W4, B4, W5, B5,
                                           W6, B6, (float*)d_out);
}

// Round 6
// 471.839 us; speedup vs baseline: 1.8367x; 1.0366x over previous
//
#include <hip/hip_runtime.h>

#define BATCH 2048

typedef unsigned short u16;
typedef __attribute__((ext_vector_type(8))) short bf16x8;  // 8 bf16 = 4 VGPR
typedef __attribute__((ext_vector_type(4))) float f32x4;   // MFMA 16x16 acc

static __device__ __forceinline__ float b2f(u16 h) {
  union { unsigned u; float f; } x; x.u = ((unsigned)h) << 16; return x.f;
}
static __device__ __forceinline__ u16 f2b(float f) {  // RNE fp32->bf16
  union { float f; unsigned u; } x; x.f = f;
  return (u16)((x.u + 0x7fffu + ((x.u >> 16) & 1u)) >> 16);
}
static __device__ __forceinline__ void split2(float v, u16& h, u16& l) {
  h = f2b(v); l = f2b(v - b2f(h));
}
// 8 bf16 from LDS at 8B alignment (2x ds_read_b64)
static __device__ __forceinline__ bf16x8 ld8u(const u16* p, int idx) {
  union { bf16x8 v; ushort4 u[2]; } x;
  x.u[0] = *(const ushort4*)(p + idx);
  x.u[1] = *(const ushort4*)(p + idx + 4);
  return x.v;
}

// ---------------------------------------------------------------------------
// Pre-split conv weights into direct-conv position-major layouts (hi plane
// then lo plane):
//   W1d [8 ky][32 oc][32 k]  k = kx*3+c for k<24, zeros k>=24  (8192 + 8192)
//   W2d [16 pos][64 oc][32 cc]                                (32768 + 32768)
//   W3d [9 pos][2 kc][64 oc][32 j]  cc = kc*32+j              (36864 + 36864)
// ---------------------------------------------------------------------------
__global__ void wsplit_kernel(const float* __restrict__ k1,
                              const float* __restrict__ k2,
                              const float* __restrict__ k3,
                              u16* __restrict__ W1d, u16* __restrict__ W2d,
                              u16* __restrict__ W3d)
{
  int id = blockIdx.x * 256 + threadIdx.x;   // 0..77823
  float v; u16 *dh, *dl;
  if (id < 8192) {
    int ky = id >> 10, oc = (id >> 5) & 31, kk = id & 31;
    if (kk < 24) {
      int kx = kk / 3, c = kk - kx * 3;
      v = k1[oc * 192 + c * 64 + ky * 8 + kx];
    } else v = 0.f;
    dh = W1d + id; dl = W1d + 8192 + id;
  } else if (id < 40960) {
    int i = id - 8192;
    int pos = i >> 11, oc = (i >> 5) & 63, cc = i & 31;
    int ky = pos >> 2, kx = pos & 3;
    v = k2[oc * 512 + cc * 16 + ky * 4 + kx];
    dh = W2d + i; dl = W2d + 32768 + i;
  } else {
    int i = id - 40960;                      // ((pos*2+kc)*64+oc)*32 + j
    int j = i & 31, oc = (i >> 5) & 63, kc = (i >> 11) & 1, pos = i >> 12;
    int ky = pos / 3, kx = pos - ky * 3;
    v = k3[oc * 576 + (kc * 32 + j) * 9 + ky * 3 + kx];
    dh = W3d + i; dl = W3d + 36864 + i;
  }
  u16 h, l; split2(v, h, l); *dh = h; *dl = l;
}

// ---------------------------------------------------------------------------
// Pre-split W1 [8][3136][64] fp32 -> W1s hi/lo bf16 in MFMA B-frag layout
// [e][chunk=k>>5][oc(64)][kk=k&31]. 1,605,632 values = grid 6272 x 256.
// ---------------------------------------------------------------------------
__global__ void w1split_kernel(const float* __restrict__ W1,
                               u16* __restrict__ W1s)
{
  int id = blockIdx.x * 256 + threadIdx.x;   // < 1605632
  int e = id / 200704;
  int r2 = id - e * 200704;
  int k = r2 >> 6, c = r2 & 63;
  float v = W1[id];
  u16 h, l; split2(v, h, l);
  int d = e * 200704 + (k >> 5) * 2048 + c * 32 + (k & 31);
  W1s[d] = h; W1s[1605632 + d] = l;
}

// ---------------------------------------------------------------------------
// Fused conv1+conv2+conv3, one block per image, 512 thr = 8 waves.
// (structure identical to the verified round-5 kernel; conv3 epilogue now
//  writes a3 pre-split to bf16 hi/lo planes for the MFMA MLP stage)
// ---------------------------------------------------------------------------
__global__ __launch_bounds__(512, 4) void conv_fused_kernel(
    const float* __restrict__ state, const u16* __restrict__ W1d,
    const u16* __restrict__ W2d, const u16* __restrict__ W3d,
    const float* __restrict__ c1, const float* __restrict__ c2,
    const float* __restrict__ c3, u16* __restrict__ a3h,
    u16* __restrict__ a3l)
{
  __shared__ __align__(16) u16 A1h[14400], A1l[14400];  // [400][36]
  __shared__ __align__(16) u16 SHa[5832], SHb[5832];    // il [20][252] / a2 [81][72]

  const int b = blockIdx.x, t = threadIdx.x;
  const int lane = t & 63, w = t >> 6, q = lane >> 4, n = lane & 15;

  // Zero the il tail: conv1's zero-weight pad lanes read past the il band.
  for (int i = t; i < 792; i += 512) { SHa[5040 + i] = 0; SHb[5040 + i] = 0; }

  // ================= conv1: 84x84x3 -> 20x20x32, 8x8 s4, 5 bands =========
  const int nT1 = (w < 2) ? 2 : 1;
  int pt1[2], ot1[2];
  if (w < 2) { pt1[0] = 0; ot1[0] = w; pt1[1] = 4; ot1[1] = w; }
  else       { pt1[0] = 1 + ((w - 2) >> 1); ot1[0] = (w - 2) & 1;
               pt1[1] = pt1[0]; ot1[1] = ot1[0]; }

  int aoff1[2];
  #pragma unroll
  for (int i = 0; i < 2; ++i) {
    int px = pt1[i] * 16 + n;                 // <= 79
    int py = (px * 205) >> 12, pxx = px - py * 20;
    aoff1[i] = (py * 4) * 252 + pxx * 12 + q * 8;
  }
  float c1v[2];
  #pragma unroll
  for (int j = 0; j < 2; ++j) c1v[j] = c1[ot1[j] * 16 + n];
  const int ob1 = (ot1[0] * 16 + n) * 32 + q * 8;   // + ky*1024

  for (int by = 0; by < 5; ++by) {
    __syncthreads();
    const float4* sp = (const float4*)(state + (size_t)b * 21168 + by * 4032);
    #pragma unroll
    for (int pass = 0; pass < 3; ++pass) {
      int i = t + pass * 512;
      if (i < 1260) {
        float4 v = sp[i];
        u16 h0, l0, h1, l1, h2, l2, h3, l3;
        split2(v.x, h0, l0); split2(v.y, h1, l1);
        split2(v.z, h2, l2); split2(v.w, h3, l3);
        ushort4 hh; hh.x = h0; hh.y = h1; hh.z = h2; hh.w = h3;
        ushort4 ll; ll.x = l0; ll.y = l1; ll.z = l2; ll.w = l3;
        *(ushort4*)&SHa[i * 4] = hh;
        *(ushort4*)&SHb[i * 4] = ll;
      }
    }
    __syncthreads();

    f32x4 acc1[2] = {};
    bf16x8 bhc = *(const bf16x8*)(W1d + ob1);
    bf16x8 boc = *(const bf16x8*)(W1d + 8192 + ob1);
    for (int ky = 0; ky < 8; ++ky) {
      const int kyn = (ky < 7) ? ky + 1 : 7;
      bf16x8 bhn = *(const bf16x8*)(W1d + kyn * 1024 + ob1);
      bf16x8 bon = *(const bf16x8*)(W1d + 8192 + kyn * 1024 + ob1);
      #pragma unroll
      for (int i = 0; i < 2; ++i) if (i < nT1) {
        bf16x8 ah = ld8u(SHa, aoff1[i] + ky * 252);
        bf16x8 al = ld8u(SHb, aoff1[i] + ky * 252);
        acc1[i] = __builtin_amdgcn_mfma_f32_16x16x32_bf16(ah, bhc, acc1[i], 0, 0, 0);
        acc1[i] = __builtin_amdgcn_mfma_f32_16x16x32_bf16(ah, boc, acc1[i], 0, 0, 0);
        acc1[i] = __builtin_amdgcn_mfma_f32_16x16x32_bf16(al, bhc, acc1[i], 0, 0, 0);
      }
      bhc = bhn; boc = bon;
    }
    #pragma unroll
    for (int i = 0; i < 2; ++i) if (i < nT1) {
      int oc = ot1[i] * 16 + n;
      #pragma unroll
      for (int r = 0; r < 4; ++r) {
        int px = by * 80 + pt1[i] * 16 + q * 4 + r;
        float v = fmaxf(acc1[i][r] + c1v[i], 0.f);
        u16 h, l; split2(v, h, l);
        A1h[px * 36 + oc] = h; A1l[px * 36 + oc] = l;
      }
    }
  }
  __syncthreads();

  // ================= conv2: 20x20x32 -> 9x9x64, 4x4 s2 ===================
  {
    const int ot2 = w & 3, pg2 = (w >> 2) * 3;
    int aoff2[3];
    #pragma unroll
    for (int i = 0; i < 3; ++i) {
      int px = (pg2 + i) * 16 + n; if (px > 80) px = 80;
      int py = (px * 7282) >> 16, pxx = px - py * 9;
      aoff2[i] = 2 * (py * 20 + pxx) * 36 + q * 8;
    }
    const float c2v = c2[ot2 * 16 + n];
    const int ob2 = (ot2 * 16 + n) * 32 + q * 8;

    f32x4 acc2[3] = {};
    bf16x8 bhc = *(const bf16x8*)(W2d + ob2);
    bf16x8 boc = *(const bf16x8*)(W2d + 32768 + ob2);
    for (int pos = 0; pos < 16; ++pos) {
      const int posn = (pos < 15) ? pos + 1 : 15;
      bf16x8 bhn = *(const bf16x8*)(W2d + posn * 2048 + ob2);
      bf16x8 bon = *(const bf16x8*)(W2d + 32768 + posn * 2048 + ob2);
      const int o = ((pos >> 2) * 20 + (pos & 3)) * 36;
      #pragma unroll
      for (int i = 0; i < 3; ++i) {
        bf16x8 ah = ld8u(A1h, aoff2[i] + o);
        bf16x8 al = ld8u(A1l, aoff2[i] + o);
        acc2[i] = __builtin_amdgcn_mfma_f32_16x16x32_bf16(ah, bhc, acc2[i], 0, 0, 0);
        acc2[i] = __builtin_amdgcn_mfma_f32_16x16x32_bf16(ah, boc, acc2[i], 0, 0, 0);
        acc2[i] = __builtin_amdgcn_mfma_f32_16x16x32_bf16(al, bhc, acc2[i], 0, 0, 0);
      }
      bhc = bhn; boc = bon;
    }
    #pragma unroll
    for (int i = 0; i < 3; ++i) {
      int oc = ot2 * 16 + n;
      #pragma unroll
      for (int r = 0; r < 4; ++r) {
        int px = (pg2 + i) * 16 + q * 4 + r;
        if (px < 81) {
          float v = fmaxf(acc2[i][r] + c2v, 0.f);
          u16 h, l; split2(v, h, l);
          SHa[px * 72 + oc] = h; SHb[px * 72 + oc] = l;
        }
      }
    }
  }
  __syncthreads();

  // ================= conv3: 9x9x64 -> 7x7x64, 3x3 s1 =====================
  {
    const int ot3 = w & 3, pg3 = (w >> 2) * 2;
    int aoff3[2];
    #pragma unroll
    for (int i = 0; i < 2; ++i) {
      int px = (pg3 + i) * 16 + n; if (px > 48) px = 48;
      int py = (px * 74) >> 9, pxx = px - py * 7;
      aoff3[i] = (py * 9 + pxx) * 72 + q * 8;
    }
    const float c3v = c3[ot3 * 16 + n];
    const int ob3 = (ot3 * 16 + n) * 32 + q * 8;

    f32x4 acc3[2] = {};
    bf16x8 bhc = *(const bf16x8*)(W3d + ob3);
    bf16x8 boc = *(const bf16x8*)(W3d + 36864 + ob3);
    for (int pk = 0; pk < 18; ++pk) {           // pk = pos*2 + kc
      const int pkn = (pk < 17) ? pk + 1 : 17;
      bf16x8 bhn = *(const bf16x8*)(W3d + pkn * 2048 + ob3);
      bf16x8 bon = *(const bf16x8*)(W3d + 36864 + pkn * 2048 + ob3);
      const int pos = pk >> 1, kc = pk & 1;
      const int ky = pos / 3, kx = pos - ky * 3;
      const int o = (ky * 9 + kx) * 72 + kc * 32;
      #pragma unroll
      for (int i = 0; i < 2; ++i) {
        bf16x8 ah = *(const bf16x8*)&SHa[aoff3[i] + o];  // 16B aligned
        bf16x8 al = *(const bf16x8*)&SHb[aoff3[i] + o];
        acc3[i] = __builtin_amdgcn_mfma_f32_16x16x32_bf16(ah, bhc, acc3[i], 0, 0, 0);
        acc3[i] = __builtin_amdgcn_mfma_f32_16x16x32_bf16(ah, boc, acc3[i], 0, 0, 0);
        acc3[i] = __builtin_amdgcn_mfma_f32_16x16x32_bf16(al, bhc, acc3[i], 0, 0, 0);
      }
      bhc = bhn; boc = bon;
    }
    u16* oph = a3h + (size_t)b * 3136;
    u16* opl = a3l + (size_t)b * 3136;
    #pragma unroll
    for (int i = 0; i < 2; ++i) {
      int oc = ot3 * 16 + n;
      #pragma unroll
      for (int r = 0; r < 4; ++r) {
        int px = (pg3 + i) * 16 + q * 4 + r;
        if (px < 49) {
          float v = fmaxf(acc3[i][r] + c3v, 0.f);
          u16 h, l; split2(v, h, l);
          oph[oc * 49 + px] = h; opl[oc * 49 + px] = l;
        }
      }
    }
  }
}

// ---------------------------------------------------------------------------
// Group samples by expert — LDS atomics (global atomic funnel was L2-bound).
// ---------------------------------------------------------------------------
__global__ void group_kernel(const void* __restrict__ rmv,
                             int* __restrict__ counts, int* __restrict__ idxb)
{
  __shared__ int lcnt[8];
  __shared__ int isI32;
  const int t = threadIdx.x;
  if (t == 0) isI32 = 0;
  if (t < 8) lcnt[t] = 0;
  __syncthreads();
  unsigned long long v = ((const unsigned long long*)rmv)[t];
  if (v >= 8ull) isI32 = 1;
  __syncthreads();
  const int i32 = isI32;
  for (int b = t; b < BATCH; b += 1024) {
    int e = i32 ? ((const int*)rmv)[b] : (int)((const long long*)rmv)[b];
    int pos = atomicAdd(&lcnt[e], 1);
    idxb[e * BATCH + pos] = b;
  }
  __syncthreads();
  if (t < 8) counts[t] = lcnt[t];
}

// ---------------------------------------------------------------------------
// Fused MLP: gemm1 (MFMA bf16 hi/lo, full K=3136, no atomics) + tail layers
// 2..6 entirely in-block. 256 blocks (e = bid>>5, tl = bid&31) x 512 thr.
// Wave (mh = w>>2, nt = w&3): 2 m-tiles x 1 n-tile, 6 MFMA/chunk.
// A-tile double-buffered in LDS [64][36] (conflict-free stride), B-frags
// direct from L2-hot W1s with cur/next rotation.
// ---------------------------------------------------------------------------
__global__ __launch_bounds__(512, 2) void mlp_kernel(
    const u16* __restrict__ a3h, const u16* __restrict__ a3l,
    const int* __restrict__ counts, const int* __restrict__ idxb,
    const u16* __restrict__ W1s, const float* __restrict__ B1,
    const float* __restrict__ W2, const float* __restrict__ B2,
    const float* __restrict__ W3, const float* __restrict__ B3,
    const float* __restrict__ W4, const float* __restrict__ B4,
    const float* __restrict__ W5, const float* __restrict__ B5,
    const float* __restrict__ W6, const float* __restrict__ B6,
    float* __restrict__ out)
{
  __shared__ __align__(16) u16 Ah[2][2304], Al[2][2304];  // [64][36] dbuf
  __shared__ __align__(16) float Wl[4096];
  __shared__ float bl[64];
  __shared__ float W6l[384];
  __shared__ float B6l[8];
  __shared__ __align__(16) float Ht0[64 * 68];
  __shared__ __align__(16) float Ht1[64 * 68];
  __shared__ int s_id[64];

  const int e  = blockIdx.x >> 5;
  const int tl = blockIdx.x & 31;
  const int cnt = counts[e];
  const int n0 = tl * 64;
  if (n0 >= cnt) return;
  const int m = min(64, cnt - n0);
  const int t = threadIdx.x;
  if (t < 64)  s_id[t] = idxb[e * BATCH + n0 + min(t, m - 1)];
  if (t < 384) W6l[t] = W6[e * 384 + t];
  if (t < 6)   B6l[t] = B6[e * 6 + t];
  __syncthreads();

  // ---- GEMM1: 64 samples x 64 outs, K = 3136 (98 chunks of 32) ----------
  const int lane = t & 63, w = t >> 6, q = lane >> 4, n = lane & 15;
  const int mh = w >> 2, nt = w & 3;
  const u16* Wb = W1s + (size_t)e * 200704;

  // staging map: thread t -> row sr = t>>3, sub = t&7 (hi kparts 0-3 / lo 0-3)
  const int sr = t >> 3, sub = t & 7, kp = sub & 3;
  const u16* srcp = (sub < 4) ? a3h : a3l;
  const size_t srow = (size_t)s_id[sr] * 3136;
  const int aro = mh * 32 + n;                  // first m-tile row for frags
  const int obase = (nt * 16 + n) * 32 + q * 8;

  f32x4 acc0 = {}, acc1 = {};
  {
    ushort4 v0 = *(const ushort4*)(srcp + srow + kp * 8);
    ushort4 v1 = *(const ushort4*)(srcp + srow + kp * 8 + 4);
    u16* dst = (sub < 4) ? Ah[0] : Al[0];
    *(ushort4*)&dst[sr * 36 + kp * 8]     = v0;
    *(ushort4*)&dst[sr * 36 + kp * 8 + 4] = v1;
  }
  bf16x8 bhc = *(const bf16x8*)(Wb + obase);
  bf16x8 boc = *(const bf16x8*)(Wb + 1605632 + obase);
  __syncthreads();

  for (int ch = 0; ch < 98; ++ch) {
    const int cur = ch & 1;
    if (ch < 97) {                              // stage next chunk into buf^1
      const int k0n = (ch + 1) * 32;
      ushort4 v0 = *(const ushort4*)(srcp + srow + k0n + kp * 8);
      ushort4 v1 = *(const ushort4*)(srcp + srow + k0n + kp * 8 + 4);
      u16* dst = (sub < 4) ? Ah[cur ^ 1] : Al[cur ^ 1];
      *(ushort4*)&dst[sr * 36 + kp * 8]     = v0;
      *(ushort4*)&dst[sr * 36 + kp * 8 + 4] = v1;
    }
    const int chn = (ch < 97) ? ch + 1 : 97;    // rotate next B-frags
    bf16x8 bhn = *(const bf16x8*)(Wb + chn * 2048 + obase);
    bf16x8 bon = *(const bf16x8*)(Wb + 1605632 + chn * 2048 + obase);

    bf16x8 a0h = ld8u(Ah[cur], aro * 36 + q * 8);
    bf16x8 a0l = ld8u(Al[cur], aro * 36 + q * 8);
    bf16x8 a1h = ld8u(Ah[cur], (aro + 16) * 36 + q * 8);
    bf16x8 a1l = ld8u(Al[cur], (aro + 16) * 36 + q * 8);
    acc0 = __builtin_amdgcn_mfma_f32_16x16x32_bf16(a0h, bhc, acc0, 0, 0, 0);
    acc0 = __builtin_amdgcn_mfma_f32_16x16x32_bf16(a0h, boc, acc0, 0, 0, 0);
    acc0 = __builtin_amdgcn_mfma_f32_16x16x32_bf16(a0l, bhc, acc0, 0, 0, 0);
    acc1 = __builtin_amdgcn_mfma_f32_16x16x32_bf16(a1h, bhc, acc1, 0, 0, 0);
    acc1 = __builtin_amdgcn_mfma_f32_16x16x32_bf16(a1h, boc, acc1, 0, 0, 0);
    acc1 = __builtin_amdgcn_mfma_f32_16x16x32_bf16(a1l, bhc, acc1, 0, 0, 0);
    bhc = bhn; boc = bon;
    __syncthreads();
  }

  // ---- H1 + bias + relu -> Ht0 [c][68] -----------------------------------
  {
    const int c = nt * 16 + n;
    const float b1v = B1[e * 64 + c];
    #pragma unroll
    for (int rr = 0; rr < 4; ++rr) {
      Ht0[c * 68 + mh * 32 + q * 4 + rr]      = fmaxf(acc0[rr] + b1v, 0.f);
      Ht0[c * 68 + mh * 32 + 16 + q * 4 + rr] = fmaxf(acc1[rr] + b1v, 0.f);
    }
  }

  // ---- tail layers 2..5 (scalar fp32, 512-thread 2x4 tiles) --------------
  const int tx = t & 15, ty = t >> 4;           // ty 0..31
  const int c0 = tx * 4, r0 = ty * 2;
  const float* Ws[4] = {W2, W3, W4, W5};
  const float* Bs[4] = {B2, B3, B4, B5};
  float* Hc = Ht0; float* Hn = Ht1;

  for (int L = 0; L < 4; ++L) {
    __syncthreads();
    const float* We = Ws[L] + (size_t)e * 4096;
    for (int i = t; i < 1024; i += 512)
      *(float4*)&Wl[i * 4] = *(const float4*)&We[i * 4];
    if (t < 64) bl[t] = Bs[L][e * 64 + t];
    __syncthreads();

    float acc[2][4] = {};
    #pragma unroll 4
    for (int kk = 0; kk < 64; ++kk) {
      float a0 = Hc[kk * 68 + r0], a1 = Hc[kk * 68 + r0 + 1];
      float4 bb = *(const float4*)&Wl[kk * 64 + c0];
      float bv[4] = {bb.x, bb.y, bb.z, bb.w};
      #pragma unroll
      for (int j = 0; j < 4; ++j) {
        acc[0][j] += a0 * bv[j];
        acc[1][j] += a1 * bv[j];
      }
    }
    __syncthreads();
    #pragma unroll
    for (int j = 0; j < 4; ++j) {
      float bias = bl[c0 + j];
      Hn[(c0 + j) * 68 + r0]     = fmaxf(acc[0][j] + bias, 0.f);
      Hn[(c0 + j) * 68 + r0 + 1] = fmaxf(acc[1][j] + bias, 0.f);
    }
    float* tmp = Hc; Hc = Hn; Hn = tmp;
  }
  __syncthreads();

  // ---- layer 6 + scatter --------------------------------------------------
  const int r = t & 63, aa = t >> 6;            // aa 0..7
  if (aa < 6) {
    float s = 0.f;
    for (int k = 0; k < 64; ++k)
      s += Hc[k * 68 + r] * W6l[k * 6 + aa];
    if (r < m) out[s_id[r] * 6 + aa] = s + B6l[aa];
  }
}

// ---------------------------------------------------------------------------
extern "C" void kernel_launch(void* const* d_in, const int* in_sizes, int n_in,
                              void* d_out, int out_size, void* d_ws, size_t ws_size,
                              hipStream_t stream) {
  const float* state = (const float*)d_in[0];
  const void*  rm    = d_in[1];
  const float* k1 = (const float*)d_in[2];
  const float* c1 = (const float*)d_in[3];
  const float* k2 = (const float*)d_in[4];
  const float* c2 = (const float*)d_in[5];
  const float* k3 = (const float*)d_in[6];
  const float* c3 = (const float*)d_in[7];
  const float* W1 = (const float*)d_in[8];
  const float* B1 = (const float*)d_in[9];
  const float* W2 = (const float*)d_in[10];
  const float* B2 = (const float*)d_in[11];
  const float* W3 = (const float*)d_in[12];
  const float* B3 = (const float*)d_in[13];
  const float* W4 = (const float*)d_in[14];
  const float* B4 = (const float*)d_in[15];
  const float* W5 = (const float*)d_in[16];
  const float* B5 = (const float*)d_in[17];
  const float* W6 = (const float*)d_in[18];
  const float* B6 = (const float*)d_in[19];

  // workspace layout (~32.5 MB; <= 66.7 MB proven-safe)
  char* ws = (char*)d_ws;
  u16* a3h    = (u16*)(ws);                    // 12,845,056
  u16* a3l    = (u16*)(ws + 12845056);         // 12,845,056 -> 25,690,112
  int* counts = (int*)(ws + 25690112);         //         32
  int* idxb   = (int*)(ws + 25690144);         //     65,536 -> 25,755,680
  u16* W1d    = (u16*)(ws + 25755680);         //     32,768 -> 25,788,448
  u16* W2d    = (u16*)(ws + 25788448);         //    131,072 -> 25,919,520
  u16* W3d    = (u16*)(ws + 25919520);         //    147,456 -> 26,066,976
  u16* W1s    = (u16*)(ws + 26066976);         //  6,422,528 -> 32,489,504

  wsplit_kernel<<<304, 256, 0, stream>>>(k1, k2, k3, W1d, W2d, W3d);
  w1split_kernel<<<6272, 256, 0, stream>>>(W1, W1s);
  group_kernel<<<1, 1024, 0, stream>>>(rm, counts, idxb);

  conv_fused_kernel<<<2048, 512, 0, stream>>>(state, W1d, W2d, W3d,
                                              c1, c2, c3, a3h, a3l);

  mlp_kernel<<<256, 512, 0, stream>>>(a3h, a3l, counts, idxb, W1s, B1,
                                      W2, B2, W3, B3, W4, B4, W5, B5,
                                      W6, B6, (float*)d_out);
}